// Round 6
// baseline (335.349 us; speedup 1.0000x reference)
//
#include <hip/hip_runtime.h>
#include <math.h>

#define NEL 10
#define FD 64
#define NBES 8
#define GG 20
#define HML 16
#define EGB 128   // edge_geom blocks (pol partials sized to this)

typedef __attribute__((ext_vector_type(8))) short short8;
typedef __attribute__((ext_vector_type(4))) float f32x4;

__device__ __forceinline__ float wred(float v) {
    #pragma unroll
    for (int off = 32; off > 0; off >>= 1) v += __shfl_down(v, off, 64);
    return v;
}

__device__ __forceinline__ float silu(float h) {
    return h / (1.f + __expf(-h));
}

__device__ __forceinline__ unsigned short f2bf(float x) {
    unsigned int b = __float_as_uint(x);
    unsigned int r = (b + 0x7FFFu + ((b >> 16) & 1u)) >> 16;
    return (unsigned short)r;
}

// Fused: species via ballot (wave == node), scal init, E0/charge, edge histogram, agg0 zero.
__global__ __launch_bounds__(256) void setup_k(
    const float* __restrict__ attrs, const float* __restrict__ ae,
    const float* __restrict__ fc, const float* __restrict__ embed_w,
    const int* __restrict__ eidx, int* __restrict__ spec,
    float* __restrict__ q, float* __restrict__ out_nodeE,
    float* __restrict__ scal, float* __restrict__ agg0,
    int* __restrict__ cnt, int N_, int E_)
{
    int idx = blockIdx.x * 256 + threadIdx.x;   // grid = N*64 threads; wave = one node
    int lane = threadIdx.x & 63;
    int n = idx >> 6;
    bool pred = (lane < NEL) && (attrs[(size_t)n * NEL + lane] > 0.5f);
    unsigned long long m = __ballot(pred);
    int sp = (int)__builtin_ctzll(m);
    scal[idx] = embed_w[sp * FD + lane];
    agg0[idx] = 0.f;
    if (lane == 0) { spec[n] = sp; q[n] = fc[sp]; out_nodeE[n] = ae[sp]; }
    if (idx < E_) atomicAdd(&cnt[eidx[E_ + idx]], 1);
}

// Shuffle-based single-block scan + W2 -> bf16 fragment-order conversion.
__global__ __launch_bounds__(1024) void scan_k(
    const int* __restrict__ cnt, int* __restrict__ cur,
    const float* __restrict__ w2, unsigned short* __restrict__ w2bf, int N_)
{
    int t = threadIdx.x;
    // convert W2[l][k][f] -> w2bf[l][f*64+k] (bf16), both layers
    #pragma unroll
    for (int ii = 0; ii < 8; ++ii) {
        int idx = ii * 1024 + t;            // = l*4096 + f*64 + k
        int l = idx >> 12, rem = idx & 4095;
        int f = rem >> 6, k = rem & 63;
        w2bf[idx] = f2bf(w2[l * 4096 + k * 64 + f]);
    }
    __shared__ int wtot[16];
    int lane = t & 63, wid = t >> 6;
    int base = t * 20;
    int c[20]; int s = 0;
    #pragma unroll
    for (int i = 0; i < 20; ++i) { int idx = base + i; c[i] = (idx < N_) ? cnt[idx] : 0; s += c[i]; }
    int v = s;
    #pragma unroll
    for (int off = 1; off < 64; off <<= 1) {
        int u = __shfl_up(v, off, 64);
        if (lane >= off) v += u;
    }
    if (lane == 63) wtot[wid] = v;
    __syncthreads();
    if (wid == 0 && lane < 16) {
        int wv = wtot[lane];
        #pragma unroll
        for (int off = 1; off < 16; off <<= 1) {
            int u = __shfl_up(wv, off, 64);
            if (lane >= off) wv += u;
        }
        wtot[lane] = wv;   // inclusive wave totals
    }
    __syncthreads();
    int ex = (wid > 0 ? wtot[wid - 1] : 0) + (v - s);
    #pragma unroll
    for (int i = 0; i < 20; ++i) {
        int idx = base + i;
        if (idx < N_) { cur[idx] = ex; ex += c[i]; }
    }
}

__global__ __launch_bounds__(256) void scatter_k(
    const int* __restrict__ eidx, int* __restrict__ cur,
    int* __restrict__ snd_s, int* __restrict__ rcv_s, int E_)
{
    int e = blockIdx.x * 256 + threadIdx.x;
    if (e < E_) {
        int r = eidx[E_ + e];
        int p = atomicAdd(&cur[r], 1);
        snd_s[p] = eidx[e];
        rcv_s[p] = r;
    }
}

// Edge geometry over SORTED edges: bessel basis (coalesced writes), flux, pol partials.
__global__ __launch_bounds__(256) void edge_geom_k(
    const float* __restrict__ pos, const int* __restrict__ snd_s,
    const int* __restrict__ rcv_s, const float* __restrict__ flux_w,
    float* __restrict__ ef, float* __restrict__ polpart, int E_, int ng)
{
    __shared__ float lpol[GG][3];
    int tid = threadIdx.x;
    if (tid < GG) { lpol[tid][0] = 0.f; lpol[tid][1] = 0.f; lpol[tid][2] = 0.f; }
    __syncthreads();
    float fw[NBES];
    #pragma unroll
    for (int i = 0; i < NBES; ++i) fw[i] = flux_w[i] + flux_w[NBES + i];
    const float PI = 3.14159265358979323846f;
    for (int p = blockIdx.x * 256 + tid; p < E_; p += EGB * 256) {
        int s = snd_s[p], r = rcv_s[p];
        float dx = pos[(size_t)r*3+0] - pos[(size_t)s*3+0];
        float dy = pos[(size_t)r*3+1] - pos[(size_t)s*3+1];
        float dz = pos[(size_t)r*3+2] - pos[(size_t)s*3+2];
        float len = sqrtf(dx*dx + dy*dy + dz*dz + 1e-12f);
        float x = len * 0.2f;
        float u = 0.f;
        if (x < 1.f) {
            float x2 = x * x;
            float x5 = x2 * x2 * x;
            u = 1.f - 21.f * x5 + 35.f * x5 * x - 15.f * x5 * x2;
        }
        float pref = 0.6324555320336759f / len * u;   // sqrt(2/5)/r * u
        float theta = PI * x;
        float s1, c1;
        __sincosf(theta, &s1, &c1);
        float c2 = 2.f * c1;
        float sp_ = 0.f, sn = s1;
        float flux = 0.f;
        float* efe = ef + (size_t)p * NBES;
        #pragma unroll
        for (int i = 0; i < NBES; ++i) {
            float rb = pref * sn;
            efe[i] = rb;
            flux += rb * fw[i];
            float nx = c2 * sn - sp_;
            sp_ = sn; sn = nx;
        }
        int g = r / ng;
        atomicAdd(&lpol[g][0], flux * dx);
        atomicAdd(&lpol[g][1], flux * dy);
        atomicAdd(&lpol[g][2], flux * dz);
    }
    __syncthreads();
    if (tid < GG * 3) polpart[blockIdx.x * (GG * 3) + tid] = lpol[tid / 3][tid % 3];
}

// Radial MLP + message + segmented scatter. Block = 4 tiles of 64 sorted edges.
// W1 columns live in VGPRs (per-thread fixed k4); B-fragments in VGPRs from
// pre-converted global bf16; phase-1 writes hsh (bf16), MFMA, ctile, segmented reduce.
__global__ __launch_bounds__(256) void edge_mlp_k(
    const float* __restrict__ ef, const int* __restrict__ snd_s,
    const int* __restrict__ rcv_s,
    const float* __restrict__ w1, const float* __restrict__ b1,
    const unsigned short* __restrict__ w2bf, const float* __restrict__ scal,
    float* __restrict__ agg0, int layer, int E_)
{
    __shared__ __align__(16) float efs[256 * 9];          // 9216 B, stride 9 (conflict-free)
    __shared__ __align__(16) unsigned short hsh[64 * 72]; // 9216 B, one tile of h (bf16)
    __shared__ __align__(16) float ctile[64 * 68];        // 17408 B, stride 68 (2-way free)
    __shared__ int sndl[256], rcvl[256];

    int t = threadIdx.x;
    int ebase = blockIdx.x * 256;
    int lane = t & 63, w = t >> 6;
    int mrow = lane & 15, quad = lane >> 4;

    sndl[t] = snd_s[ebase + t];
    rcvl[t] = rcv_s[ebase + t];
    {
        const f32x4* e4 = (const f32x4*)(ef + (size_t)(ebase + t) * NBES);
        f32x4 A0 = e4[0], A1 = e4[1];
        #pragma unroll
        for (int i = 0; i < 4; ++i) { efs[t*9 + i] = A0[i]; efs[t*9 + 4 + i] = A1[i]; }
    }
    // per-thread W1 column block: k4 = (t&15)*4
    int k4 = (t & 15) * 4;
    f32x4 bias4 = *(const f32x4*)&b1[layer * FD + k4];
    f32x4 wrow[8];
    #pragma unroll
    for (int i = 0; i < 8; ++i) wrow[i] = *(const f32x4*)&w1[(layer * 8 + i) * FD + k4];
    // B fragments in registers (shared by all 4 tiles)
    const unsigned short* wb = w2bf + layer * 4096;
    short8 bf0[4], bf1[4];
    #pragma unroll
    for (int nt = 0; nt < 4; ++nt) {
        bf0[nt] = *(const short8*)&wb[(nt * 16 + mrow) * 64 + quad * 8];
        bf1[nt] = *(const short8*)&wb[(nt * 16 + mrow) * 64 + 32 + quad * 8];
    }
    __syncthreads();

    int ehi = t >> 4;   // 0..15
    for (int tau = 0; tau < 4; ++tau) {
        // phase 1: thread computes h[e][k4..k4+3] for 4 edges
        #pragma unroll
        for (int j = 0; j < 4; ++j) {
            int eloc = 16 * j + ehi;                 // tile-local edge 0..63
            int e = tau * 64 + eloc;                 // block-local (efs index)
            float er[8];
            #pragma unroll
            for (int i = 0; i < 8; ++i) er[i] = efs[e * 9 + i];
            f32x4 h = bias4;
            #pragma unroll
            for (int i = 0; i < 8; ++i) h += wrow[i] * er[i];
            unsigned int p0 = (unsigned int)f2bf(silu(h.x)) | ((unsigned int)f2bf(silu(h.y)) << 16);
            unsigned int p1 = (unsigned int)f2bf(silu(h.z)) | ((unsigned int)f2bf(silu(h.w)) << 16);
            unsigned int* hp = (unsigned int*)&hsh[eloc * 72];
            hp[(t & 15) * 2 + 0] = p0;
            hp[(t & 15) * 2 + 1] = p1;
        }
        __syncthreads();

        // phase 2: A-frags from hsh, 8 MFMAs per wave
        short8 a0 = *(const short8*)&hsh[(16 * w + mrow) * 72 + quad * 8];
        short8 a1 = *(const short8*)&hsh[(16 * w + mrow) * 72 + 32 + quad * 8];
        f32x4 c[4];
        #pragma unroll
        for (int nt = 0; nt < 4; ++nt) {
            f32x4 cc = {0.f, 0.f, 0.f, 0.f};
            cc = __builtin_amdgcn_mfma_f32_16x16x32_bf16(a0, bf0[nt], cc, 0, 0, 0);
            cc = __builtin_amdgcn_mfma_f32_16x16x32_bf16(a1, bf1[nt], cc, 0, 0, 0);
            c[nt] = cc;
        }
        #pragma unroll
        for (int nt = 0; nt < 4; ++nt)
            #pragma unroll
            for (int reg = 0; reg < 4; ++reg)
                ctile[(16 * w + quad * 4 + reg) * 68 + nt * 16 + mrow] = c[nt][reg];
        __syncthreads();

        // epilogue: wave w reduces its 16 sorted positions of this tile
        int f = lane;
        int pb = tau * 64 + 16 * w;
        int curR = rcvl[pb];
        float run = 0.f;
        #pragma unroll
        for (int pp = 0; pp < 16; ++pp) {
            int p = pb + pp;
            float v = ctile[(16 * w + pp) * 68 + f] * scal[(size_t)sndl[p] * FD + f];
            int r = rcvl[p];
            if (r != curR) {
                atomicAdd(&agg0[(size_t)curR * FD + f], run);
                run = v; curR = r;
            } else {
                run += v;
            }
        }
        atomicAdd(&agg0[(size_t)curR * FD + f], run);
    }
}

// Node update: scalars' = agg/16 + (agg/16)^2 + scal*prod_w[spec]; per-node energies to scratch.
__global__ __launch_bounds__(256) void node_update_k(
    float* __restrict__ scal, float* __restrict__ agg0,
    const int* __restrict__ spec, const float* __restrict__ prod_w,
    const float* __restrict__ readout_w, const float* __restrict__ ro2_w1,
    const float* __restrict__ ro2_b1, const float* __restrict__ ro2_w2,
    const float* __restrict__ charge_w, float* __restrict__ q,
    float* __restrict__ out_nodeE, float* __restrict__ nEl,
    int layer, int last, int N_)
{
    __shared__ float vsh[4][FD];
    int wid = threadIdx.x >> 6, lane = threadIdx.x & 63;
    int n = blockIdx.x * 4 + wid;
    int sp = spec[n];
    size_t idx = (size_t)n * FD + lane;
    float a = agg0[idx] * 0.0625f;
    agg0[idx] = 0.f;                       // pre-zero for next layer
    float v = a + a * a + scal[idx] * prod_w[(layer * NEL + sp) * FD + lane];
    scal[idx] = v;

    float ne;
    if (!last) {
        ne = wred(v * readout_w[layer * FD + lane]);
    } else {
        vsh[wid][lane] = v;
        __syncthreads();
        float h = 0.f;
        if (lane < HML) {
            h = ro2_b1[lane];
            for (int ff = 0; ff < FD; ++ff) h += vsh[wid][ff] * ro2_w1[ff * HML + lane];
            h = silu(h) * ro2_w2[lane];
        }
        ne = wred(h);
    }
    float qs = wred(v * charge_w[layer * FD + lane]);
    if (lane == 0) {
        nEl[n] = ne;
        out_nodeE[n] += ne;
        q[n] += qs;
    }
}

// Direct screened Coulomb: block = (graph, 64-wide i-chunk, 250-wide j-slice). 1280 blocks.
__global__ __launch_bounds__(256) void coulomb_k(
    const float* __restrict__ q, const float* __restrict__ pos,
    float* __restrict__ eel, int ng)
{
    __shared__ float qs[250], jx[250], jy[250], jz[250];
    __shared__ float wsum[4];
    int bid = blockIdx.x;
    int g = bid >> 6, rem = bid & 63;
    int ic = rem >> 2, jc = rem & 3;
    int tid = threadIdx.x, lane = tid & 63, w = tid >> 6;
    const float* qg = q + (size_t)g * ng;
    const float* pg = pos + (size_t)g * ng * 3;
    int jbase = jc * 250;
    if (tid < 250) {
        int j = jbase + tid;
        qs[tid] = qg[j];
        jx[tid] = pg[(size_t)j*3+0]; jy[tid] = pg[(size_t)j*3+1]; jz[tid] = pg[(size_t)j*3+2];
    }
    __syncthreads();
    int i = ic * 64 + lane;
    float acc = 0.f;
    if (i < ng) {
        float qi = qg[i];
        float xi = pg[(size_t)i*3+0], yi = pg[(size_t)i*3+1], zi = pg[(size_t)i*3+2];
        for (int jj = w; jj < 250; jj += 4) {     // jj wave-uniform -> LDS broadcast
            int j = jbase + jj;
            float dx = xi - jx[jj], dy = yi - jy[jj], dz = zi - jz[jj];
            float d2 = dx*dx + dy*dy + dz*dz + 1e-12f;
            float rinv = __frsqrt_rn(d2);
            float r = d2 * rinv;
            float x = 0.5f * r;
            float tt = __frcp_rn(1.f + 0.3275911f * x);
            float poly = ((((1.061405429f*tt - 1.453152027f)*tt + 1.421413741f)*tt
                           - 0.284496736f)*tt + 0.254829592f)*tt;
            float erfv = 1.f - poly * __expf(-x * x);
            float kern = (j == i) ? 0.f : erfv * rinv;
            acc += qi * qs[jj] * kern;
        }
    }
    acc = wred(acc);
    if (lane == 0) wsum[w] = acc;
    __syncthreads();
    if (tid == 0) atomicAdd(&eel[g], 0.5f * (wsum[0] + wsum[1] + wsum[2] + wsum[3]));
}

// Per-graph reductions + final output assembly (runs after coulomb).
__global__ __launch_bounds__(256) void graph_final_k(
    const int* __restrict__ spec, const float* __restrict__ ae,
    const float* __restrict__ fc, const float* __restrict__ pos,
    const float* __restrict__ q, const float* __restrict__ nE0,
    const float* __restrict__ nE1, const float* __restrict__ polpart,
    const float* __restrict__ eel, float* __restrict__ out,
    int ng, int N_)
{
    __shared__ float red[4][8];
    __shared__ float res[7];
    int g = blockIdx.x;
    int tid = threadIdx.x, wid = tid >> 6, lane = tid & 63;
    float se0 = 0.f, s0 = 0.f, s1 = 0.f, sq = 0.f, p0 = 0.f, p1 = 0.f, p2 = 0.f;
    for (int n = g * ng + tid; n < (g + 1) * ng; n += 256) {
        int sp = spec[n];
        float fq = fc[sp];
        se0 += ae[sp];
        s0 += nE0[n];
        s1 += nE1[n];
        sq += q[n];
        p0 += fq * pos[(size_t)n*3+0];
        p1 += fq * pos[(size_t)n*3+1];
        p2 += fq * pos[(size_t)n*3+2];
    }
    float vals[7] = {se0, s0, s1, sq, p0, p1, p2};
    #pragma unroll
    for (int k = 0; k < 7; ++k) {
        float r = wred(vals[k]);
        if (lane == 0) red[wid][k] = r;
    }
    __syncthreads();
    if (tid < 7) {
        float s = red[0][tid] + red[1][tid] + red[2][tid] + red[3][tid];
        if (tid >= 4) {
            int cdim = tid - 4;
            for (int b = 0; b < EGB; ++b) s += polpart[b * (GG * 3) + g * 3 + cdim];
        }
        res[tid] = s;
    }
    __syncthreads();
    if (tid == 0) {
        int G_ = GG;
        float a0 = res[0], a1 = res[1], a2 = res[2];
        out[g] = a0 + a1 + a2 + eel[g];             // total_energy
        float* contrib = out + G_ + N_;             // contributions [G,3]
        contrib[g*3+0] = a0; contrib[g*3+1] = a1; contrib[g*3+2] = a2;
        float* pol = contrib + G_ * 3;              // pol [G,3]
        pol[g*3+0] = res[4]; pol[g*3+1] = res[5]; pol[g*3+2] = res[6];
        float* qt = pol + G_ * 3;                   // total_charge [G]
        qt[g] = res[3];
    }
}

extern "C" void kernel_launch(void* const* d_in, const int* in_sizes, int n_in,
                              void* d_out, int out_size, void* d_ws, size_t ws_size,
                              hipStream_t stream)
{
    const float* node_attrs      = (const float*)d_in[0];
    const float* positions       = (const float*)d_in[1];
    const int*   edge_index      = (const int*)d_in[2];
    const float* atomic_energies = (const float*)d_in[5];
    const float* embed_w         = (const float*)d_in[6];
    const float* radial_w1       = (const float*)d_in[7];
    const float* radial_b1       = (const float*)d_in[8];
    const float* radial_w2       = (const float*)d_in[9];
    const float* prod_w          = (const float*)d_in[10];
    const float* readout_w       = (const float*)d_in[11];
    const float* ro2_w1          = (const float*)d_in[12];
    const float* ro2_b1          = (const float*)d_in[13];
    const float* ro2_w2          = (const float*)d_in[14];
    const float* charge_w        = (const float*)d_in[15];
    const float* flux_w          = (const float*)d_in[16];
    const float* formal_charges  = (const float*)d_in[17];

    int N = in_sizes[0] / NEL;     // 20000
    int E = in_sizes[2] / 2;       // 320000
    const int G_ = GG;             // 20
    int ng = N / G_;               // 1000

    float* ws      = (float*)d_ws;
    float* scal    = ws;                               // [N,64]
    float* agg0    = scal + (size_t)N * FD;            // [N,64]
    float* ef      = agg0 + (size_t)N * FD;            // [E,8] (sorted order)
    float* q       = ef + (size_t)E * NBES;            // [N]
    int*   spec    = (int*)(q + N);                    // [N]
    float* nE0     = (float*)(spec + N);               // [N]
    float* nE1     = nE0 + N;                          // [N]
    float* polpart = nE1 + N;                          // [EGB*60]
    int*   cnt     = (int*)(polpart + EGB * (GG * 3)); // [N]
    float* acc     = (float*)(cnt + N);                // [160] (contiguous w/ cnt for 1 memset)
    int*   cur     = (int*)(acc + 160);                // [N]
    int*   snd_s   = cur + N;                          // [E]
    int*   rcv_s   = snd_s + E;                        // [E]
    unsigned short* w2bf = (unsigned short*)(rcv_s + E); // [2*4096] bf16, 16B-aligned

    float* out = (float*)d_out;
    float* out_nodeE = out + G_;

    hipMemsetAsync(cnt, 0, (size_t)N * sizeof(int) + 160 * sizeof(float), stream);

    setup_k<<<(N * FD) / 256, 256, 0, stream>>>(
        node_attrs, atomic_energies, formal_charges, embed_w, edge_index,
        spec, q, out_nodeE, scal, agg0, cnt, N, E);
    scan_k<<<1, 1024, 0, stream>>>(cnt, cur, radial_w2, w2bf, N);
    scatter_k<<<(E + 255) / 256, 256, 0, stream>>>(edge_index, cur, snd_s, rcv_s, E);

    edge_geom_k<<<EGB, 256, 0, stream>>>(positions, snd_s, rcv_s, flux_w, ef, polpart, E, ng);

    for (int l = 0; l < 2; ++l) {
        edge_mlp_k<<<E / 256, 256, 0, stream>>>(
            ef, snd_s, rcv_s, radial_w1, radial_b1, w2bf, scal, agg0, l, E);
        node_update_k<<<N / 4, 256, 0, stream>>>(
            scal, agg0, spec, prod_w, readout_w, ro2_w1, ro2_b1, ro2_w2,
            charge_w, q, out_nodeE, (l == 0) ? nE0 : nE1,
            l, (l == 1) ? 1 : 0, N);
    }

    coulomb_k<<<G_ * 64, 256, 0, stream>>>(q, positions, acc + 60, ng);
    graph_final_k<<<G_, 256, 0, stream>>>(spec, atomic_energies, formal_charges,
                                          positions, q, nE0, nE1, polpart,
                                          acc + 60, out, ng, N);
}

// Round 7
// 318.550 us; speedup vs baseline: 1.0527x; 1.0527x over previous
//
#include <hip/hip_runtime.h>
#include <math.h>

#define NEL 10
#define FD 64
#define NBES 8
#define GG 20
#define HML 16
#define EGB 512   // edge_geom blocks (pol partials sized to this)

typedef __attribute__((ext_vector_type(8))) short short8;
typedef __attribute__((ext_vector_type(4))) float f32x4;

__device__ __forceinline__ float wred(float v) {
    #pragma unroll
    for (int off = 32; off > 0; off >>= 1) v += __shfl_down(v, off, 64);
    return v;
}

__device__ __forceinline__ float silu(float h) {
    return h / (1.f + __expf(-h));
}

__device__ __forceinline__ unsigned short f2bf(float x) {
    unsigned int b = __float_as_uint(x);
    unsigned int r = (b + 0x7FFFu + ((b >> 16) & 1u)) >> 16;
    return (unsigned short)r;
}

// Fused: species via ballot (wave == node), scal init, E0/charge, edge histogram, agg0 zero.
__global__ __launch_bounds__(256) void setup_k(
    const float* __restrict__ attrs, const float* __restrict__ ae,
    const float* __restrict__ fc, const float* __restrict__ embed_w,
    const int* __restrict__ eidx, int* __restrict__ spec,
    float* __restrict__ q, float* __restrict__ out_nodeE,
    float* __restrict__ scal, float* __restrict__ agg0,
    int* __restrict__ cnt, int N_, int E_)
{
    int idx = blockIdx.x * 256 + threadIdx.x;   // grid = N*64 threads; wave = one node
    int lane = threadIdx.x & 63;
    int n = idx >> 6;
    bool pred = (lane < NEL) && (attrs[(size_t)n * NEL + lane] > 0.5f);
    unsigned long long m = __ballot(pred);
    int sp = (int)__builtin_ctzll(m);
    scal[idx] = embed_w[sp * FD + lane];
    agg0[idx] = 0.f;
    if (lane == 0) { spec[n] = sp; q[n] = fc[sp]; out_nodeE[n] = ae[sp]; }
    if (idx < E_) atomicAdd(&cnt[eidx[E_ + idx]], 1);
}

// Shuffle-based single-block scan + W2 -> bf16 fragment-order conversion.
__global__ __launch_bounds__(1024) void scan_k(
    const int* __restrict__ cnt, int* __restrict__ cur,
    const float* __restrict__ w2, unsigned short* __restrict__ w2bf, int N_)
{
    int t = threadIdx.x;
    // convert W2[l][k][f] -> w2bf[l][f*64+k] (bf16), both layers
    #pragma unroll
    for (int ii = 0; ii < 8; ++ii) {
        int idx = ii * 1024 + t;            // = l*4096 + f*64 + k
        int l = idx >> 12, rem = idx & 4095;
        int f = rem >> 6, k = rem & 63;
        w2bf[idx] = f2bf(w2[l * 4096 + k * 64 + f]);
    }
    __shared__ int wtot[16];
    int lane = t & 63, wid = t >> 6;
    int base = t * 20;
    int c[20]; int s = 0;
    #pragma unroll
    for (int i = 0; i < 20; ++i) { int idx = base + i; c[i] = (idx < N_) ? cnt[idx] : 0; s += c[i]; }
    int v = s;
    #pragma unroll
    for (int off = 1; off < 64; off <<= 1) {
        int u = __shfl_up(v, off, 64);
        if (lane >= off) v += u;
    }
    if (lane == 63) wtot[wid] = v;
    __syncthreads();
    if (wid == 0 && lane < 16) {
        int wv = wtot[lane];
        #pragma unroll
        for (int off = 1; off < 16; off <<= 1) {
            int u = __shfl_up(wv, off, 64);
            if (lane >= off) wv += u;
        }
        wtot[lane] = wv;   // inclusive wave totals
    }
    __syncthreads();
    int ex = (wid > 0 ? wtot[wid - 1] : 0) + (v - s);
    #pragma unroll
    for (int i = 0; i < 20; ++i) {
        int idx = base + i;
        if (idx < N_) { cur[idx] = ex; ex += c[i]; }
    }
}

__global__ __launch_bounds__(256) void scatter_k(
    const int* __restrict__ eidx, int* __restrict__ cur,
    int* __restrict__ snd_s, int* __restrict__ rcv_s, int E_)
{
    int e = blockIdx.x * 256 + threadIdx.x;
    if (e < E_) {
        int r = eidx[E_ + e];
        int p = atomicAdd(&cur[r], 1);
        snd_s[p] = eidx[e];
        rcv_s[p] = r;
    }
}

// Edge geometry over SORTED edges: bessel basis (coalesced writes), flux, pol partials.
__global__ __launch_bounds__(256) void edge_geom_k(
    const float* __restrict__ pos, const int* __restrict__ snd_s,
    const int* __restrict__ rcv_s, const float* __restrict__ flux_w,
    float* __restrict__ ef, float* __restrict__ polpart, int E_, int ng)
{
    __shared__ float lpol[GG][3];
    int tid = threadIdx.x;
    if (tid < GG) { lpol[tid][0] = 0.f; lpol[tid][1] = 0.f; lpol[tid][2] = 0.f; }
    __syncthreads();
    float fw[NBES];
    #pragma unroll
    for (int i = 0; i < NBES; ++i) fw[i] = flux_w[i] + flux_w[NBES + i];
    const float PI = 3.14159265358979323846f;
    for (int p = blockIdx.x * 256 + tid; p < E_; p += EGB * 256) {
        int s = snd_s[p], r = rcv_s[p];
        float dx = pos[(size_t)r*3+0] - pos[(size_t)s*3+0];
        float dy = pos[(size_t)r*3+1] - pos[(size_t)s*3+1];
        float dz = pos[(size_t)r*3+2] - pos[(size_t)s*3+2];
        float len = sqrtf(dx*dx + dy*dy + dz*dz + 1e-12f);
        float x = len * 0.2f;
        float u = 0.f;
        if (x < 1.f) {
            float x2 = x * x;
            float x5 = x2 * x2 * x;
            u = 1.f - 21.f * x5 + 35.f * x5 * x - 15.f * x5 * x2;
        }
        float pref = 0.6324555320336759f / len * u;   // sqrt(2/5)/r * u
        float theta = PI * x;
        float s1, c1;
        __sincosf(theta, &s1, &c1);
        float c2 = 2.f * c1;
        float sp_ = 0.f, sn = s1;
        float flux = 0.f;
        float* efe = ef + (size_t)p * NBES;
        #pragma unroll
        for (int i = 0; i < NBES; ++i) {
            float rb = pref * sn;
            efe[i] = rb;
            flux += rb * fw[i];
            float nx = c2 * sn - sp_;
            sp_ = sn; sn = nx;
        }
        int g = r / ng;
        atomicAdd(&lpol[g][0], flux * dx);
        atomicAdd(&lpol[g][1], flux * dy);
        atomicAdd(&lpol[g][2], flux * dz);
    }
    __syncthreads();
    if (tid < GG * 3) polpart[blockIdx.x * (GG * 3) + tid] = lpol[tid / 3][tid % 3];
}

// Radial MLP + message + segmented scatter. WAVE-INDEPENDENT: each wave owns a
// 16-edge tile with private LDS slices -> ZERO __syncthreads (DS ops within a
// wave are ordered; compiler inserts lgkmcnt waits). W1 columns + B-fragments
// in VGPRs.
__global__ __launch_bounds__(256) void edge_mlp_k(
    const float* __restrict__ ef, const int* __restrict__ snd_s,
    const int* __restrict__ rcv_s,
    const float* __restrict__ w1, const float* __restrict__ b1,
    const unsigned short* __restrict__ w2bf, const float* __restrict__ scal,
    float* __restrict__ agg0, int layer, int E_)
{
    __shared__ __align__(16) float efs[4][16 * 8];            // 2048 B
    __shared__ __align__(16) unsigned short hsh[4][16 * 72];  // 9216 B (stride 72 shorts = 144 B, 16B-mult)
    __shared__ __align__(16) float ctile[4][16 * 68];         // 17408 B (stride 68: 2-way = free)
    __shared__ int sndl[4][16], rcvl[4][16];

    int t = threadIdx.x, w = t >> 6, lane = t & 63;
    int mrow = lane & 15, quad = lane >> 4;
    int ebase = (blockIdx.x * 4 + w) * 16;

    // stage (all wave-local)
    if (lane < 16) {
        sndl[w][lane] = snd_s[ebase + lane];
        rcvl[w][lane] = rcv_s[ebase + lane];
    }
    {
        const float2* src = (const float2*)(ef + (size_t)ebase * NBES);
        float2 v = src[lane];                      // 128 floats, 2/lane, coalesced
        *(float2*)&efs[w][lane * 2] = v;
    }
    // W1 column k = lane (9 VGPRs)
    float bias = b1[layer * FD + lane];
    float w1c[8];
    #pragma unroll
    for (int i = 0; i < 8; ++i) w1c[i] = w1[(layer * 8 + i) * FD + lane];
    // B fragments in VGPRs
    const unsigned short* wb = w2bf + layer * 4096;
    short8 bf0[4], bf1[4];
    #pragma unroll
    for (int nt = 0; nt < 4; ++nt) {
        bf0[nt] = *(const short8*)&wb[(nt * 16 + mrow) * 64 + quad * 8];
        bf1[nt] = *(const short8*)&wb[(nt * 16 + mrow) * 64 + 32 + quad * 8];
    }

    // phase 1: h[e][lane] = silu(ef[e]@W1col + b); broadcast reads, wave-local
    #pragma unroll
    for (int e = 0; e < 16; ++e) {
        float h = bias;
        #pragma unroll
        for (int i = 0; i < 8; ++i) h += efs[w][e * 8 + i] * w1c[i];
        hsh[w][e * 72 + lane] = f2bf(silu(h));
    }

    // phase 2: A-frags (wave-local hsh), 8 MFMAs
    short8 a0 = *(const short8*)&hsh[w][mrow * 72 + quad * 8];
    short8 a1 = *(const short8*)&hsh[w][mrow * 72 + 32 + quad * 8];
    f32x4 c[4];
    #pragma unroll
    for (int nt = 0; nt < 4; ++nt) {
        f32x4 cc = {0.f, 0.f, 0.f, 0.f};
        cc = __builtin_amdgcn_mfma_f32_16x16x32_bf16(a0, bf0[nt], cc, 0, 0, 0);
        cc = __builtin_amdgcn_mfma_f32_16x16x32_bf16(a1, bf1[nt], cc, 0, 0, 0);
        c[nt] = cc;
    }
    // transpose C via wave-local ctile: row = edge = quad*4+reg, col = nt*16+mrow
    #pragma unroll
    for (int nt = 0; nt < 4; ++nt)
        #pragma unroll
        for (int reg = 0; reg < 4; ++reg)
            ctile[w][(quad * 4 + reg) * 68 + nt * 16 + mrow] = c[nt][reg];

    // epilogue: segmented reduce over the wave's 16 sorted positions
    int curR = rcvl[w][0];
    float run = 0.f;
    #pragma unroll
    for (int pp = 0; pp < 16; ++pp) {
        float v = ctile[w][pp * 68 + lane] * scal[(size_t)sndl[w][pp] * FD + lane];
        int r = rcvl[w][pp];
        if (r != curR) {
            atomicAdd(&agg0[(size_t)curR * FD + lane], run);
            run = v; curR = r;
        } else {
            run += v;
        }
    }
    atomicAdd(&agg0[(size_t)curR * FD + lane], run);
}

// Node update: scalars' = agg/16 + (agg/16)^2 + scal*prod_w[spec]; per-node energies to scratch.
__global__ __launch_bounds__(256) void node_update_k(
    float* __restrict__ scal, float* __restrict__ agg0,
    const int* __restrict__ spec, const float* __restrict__ prod_w,
    const float* __restrict__ readout_w, const float* __restrict__ ro2_w1,
    const float* __restrict__ ro2_b1, const float* __restrict__ ro2_w2,
    const float* __restrict__ charge_w, float* __restrict__ q,
    float* __restrict__ out_nodeE, float* __restrict__ nEl,
    int layer, int last, int N_)
{
    __shared__ float vsh[4][FD];
    int wid = threadIdx.x >> 6, lane = threadIdx.x & 63;
    int n = blockIdx.x * 4 + wid;
    int sp = spec[n];
    size_t idx = (size_t)n * FD + lane;
    float a = agg0[idx] * 0.0625f;
    agg0[idx] = 0.f;                       // pre-zero for next layer
    float v = a + a * a + scal[idx] * prod_w[(layer * NEL + sp) * FD + lane];
    scal[idx] = v;

    float ne;
    if (!last) {
        ne = wred(v * readout_w[layer * FD + lane]);
    } else {
        vsh[wid][lane] = v;
        __syncthreads();
        float h = 0.f;
        if (lane < HML) {
            h = ro2_b1[lane];
            for (int ff = 0; ff < FD; ++ff) h += vsh[wid][ff] * ro2_w1[ff * HML + lane];
            h = silu(h) * ro2_w2[lane];
        }
        ne = wred(h);
    }
    float qs = wred(v * charge_w[layer * FD + lane]);
    if (lane == 0) {
        nEl[n] = ne;
        out_nodeE[n] += ne;
        q[n] += qs;
    }
}

// Direct screened Coulomb: block = (graph, 64-wide i-chunk, 250-wide j-slice). 1280 blocks.
__global__ __launch_bounds__(256) void coulomb_k(
    const float* __restrict__ q, const float* __restrict__ pos,
    float* __restrict__ eel, int ng)
{
    __shared__ float qs[250], jx[250], jy[250], jz[250];
    __shared__ float wsum[4];
    int bid = blockIdx.x;
    int g = bid >> 6, rem = bid & 63;
    int ic = rem >> 2, jc = rem & 3;
    int tid = threadIdx.x, lane = tid & 63, w = tid >> 6;
    const float* qg = q + (size_t)g * ng;
    const float* pg = pos + (size_t)g * ng * 3;
    int jbase = jc * 250;
    if (tid < 250) {
        int j = jbase + tid;
        qs[tid] = qg[j];
        jx[tid] = pg[(size_t)j*3+0]; jy[tid] = pg[(size_t)j*3+1]; jz[tid] = pg[(size_t)j*3+2];
    }
    __syncthreads();
    int i = ic * 64 + lane;
    float acc = 0.f;
    if (i < ng) {
        float qi = qg[i];
        float xi = pg[(size_t)i*3+0], yi = pg[(size_t)i*3+1], zi = pg[(size_t)i*3+2];
        for (int jj = w; jj < 250; jj += 4) {     // jj wave-uniform -> LDS broadcast
            int j = jbase + jj;
            float dx = xi - jx[jj], dy = yi - jy[jj], dz = zi - jz[jj];
            float d2 = dx*dx + dy*dy + dz*dz + 1e-12f;
            float rinv = __frsqrt_rn(d2);
            float r = d2 * rinv;
            float x = 0.5f * r;
            float tt = __frcp_rn(1.f + 0.3275911f * x);
            float poly = ((((1.061405429f*tt - 1.453152027f)*tt + 1.421413741f)*tt
                           - 0.284496736f)*tt + 0.254829592f)*tt;
            float erfv = 1.f - poly * __expf(-x * x);
            float kern = (j == i) ? 0.f : erfv * rinv;
            acc += qi * qs[jj] * kern;
        }
    }
    acc = wred(acc);
    if (lane == 0) wsum[w] = acc;
    __syncthreads();
    if (tid == 0) atomicAdd(&eel[g], 0.5f * (wsum[0] + wsum[1] + wsum[2] + wsum[3]));
}

// Per-graph reductions + final output assembly (runs after coulomb).
__global__ __launch_bounds__(256) void graph_final_k(
    const int* __restrict__ spec, const float* __restrict__ ae,
    const float* __restrict__ fc, const float* __restrict__ pos,
    const float* __restrict__ q, const float* __restrict__ nE0,
    const float* __restrict__ nE1, const float* __restrict__ polpart,
    const float* __restrict__ eel, float* __restrict__ out,
    int ng, int N_)
{
    __shared__ float red[4][8];
    __shared__ float res[7];
    int g = blockIdx.x;
    int tid = threadIdx.x, wid = tid >> 6, lane = tid & 63;
    float se0 = 0.f, s0 = 0.f, s1 = 0.f, sq = 0.f, p0 = 0.f, p1 = 0.f, p2 = 0.f;
    for (int n = g * ng + tid; n < (g + 1) * ng; n += 256) {
        int sp = spec[n];
        float fq = fc[sp];
        se0 += ae[sp];
        s0 += nE0[n];
        s1 += nE1[n];
        sq += q[n];
        p0 += fq * pos[(size_t)n*3+0];
        p1 += fq * pos[(size_t)n*3+1];
        p2 += fq * pos[(size_t)n*3+2];
    }
    float vals[7] = {se0, s0, s1, sq, p0, p1, p2};
    #pragma unroll
    for (int k = 0; k < 7; ++k) {
        float r = wred(vals[k]);
        if (lane == 0) red[wid][k] = r;
    }
    __syncthreads();
    if (tid < 7) {
        float s = red[0][tid] + red[1][tid] + red[2][tid] + red[3][tid];
        if (tid >= 4) {
            int cdim = tid - 4;
            for (int b = 0; b < EGB; ++b) s += polpart[b * (GG * 3) + g * 3 + cdim];
        }
        res[tid] = s;
    }
    __syncthreads();
    if (tid == 0) {
        int G_ = GG;
        float a0 = res[0], a1 = res[1], a2 = res[2];
        out[g] = a0 + a1 + a2 + eel[g];             // total_energy
        float* contrib = out + G_ + N_;             // contributions [G,3]
        contrib[g*3+0] = a0; contrib[g*3+1] = a1; contrib[g*3+2] = a2;
        float* pol = contrib + G_ * 3;              // pol [G,3]
        pol[g*3+0] = res[4]; pol[g*3+1] = res[5]; pol[g*3+2] = res[6];
        float* qt = pol + G_ * 3;                   // total_charge [G]
        qt[g] = res[3];
    }
}

extern "C" void kernel_launch(void* const* d_in, const int* in_sizes, int n_in,
                              void* d_out, int out_size, void* d_ws, size_t ws_size,
                              hipStream_t stream)
{
    const float* node_attrs      = (const float*)d_in[0];
    const float* positions       = (const float*)d_in[1];
    const int*   edge_index      = (const int*)d_in[2];
    const float* atomic_energies = (const float*)d_in[5];
    const float* embed_w         = (const float*)d_in[6];
    const float* radial_w1       = (const float*)d_in[7];
    const float* radial_b1       = (const float*)d_in[8];
    const float* radial_w2       = (const float*)d_in[9];
    const float* prod_w          = (const float*)d_in[10];
    const float* readout_w       = (const float*)d_in[11];
    const float* ro2_w1          = (const float*)d_in[12];
    const float* ro2_b1          = (const float*)d_in[13];
    const float* ro2_w2          = (const float*)d_in[14];
    const float* charge_w        = (const float*)d_in[15];
    const float* flux_w          = (const float*)d_in[16];
    const float* formal_charges  = (const float*)d_in[17];

    int N = in_sizes[0] / NEL;     // 20000
    int E = in_sizes[2] / 2;       // 320000
    const int G_ = GG;             // 20
    int ng = N / G_;               // 1000

    float* ws      = (float*)d_ws;
    float* scal    = ws;                               // [N,64]
    float* agg0    = scal + (size_t)N * FD;            // [N,64]
    float* ef      = agg0 + (size_t)N * FD;            // [E,8] (sorted order)
    float* q       = ef + (size_t)E * NBES;            // [N]
    int*   spec    = (int*)(q + N);                    // [N]
    float* nE0     = (float*)(spec + N);               // [N]
    float* nE1     = nE0 + N;                          // [N]
    float* polpart = nE1 + N;                          // [EGB*60]
    int*   cnt     = (int*)(polpart + EGB * (GG * 3)); // [N]
    float* acc     = (float*)(cnt + N);                // [160] (contiguous w/ cnt for 1 memset)
    int*   cur     = (int*)(acc + 160);                // [N]
    int*   snd_s   = cur + N;                          // [E]
    int*   rcv_s   = snd_s + E;                        // [E]
    unsigned short* w2bf = (unsigned short*)(rcv_s + E); // [2*4096] bf16, 16B-aligned

    float* out = (float*)d_out;
    float* out_nodeE = out + G_;

    hipMemsetAsync(cnt, 0, (size_t)N * sizeof(int) + 160 * sizeof(float), stream);

    setup_k<<<(N * FD) / 256, 256, 0, stream>>>(
        node_attrs, atomic_energies, formal_charges, embed_w, edge_index,
        spec, q, out_nodeE, scal, agg0, cnt, N, E);
    scan_k<<<1, 1024, 0, stream>>>(cnt, cur, radial_w2, w2bf, N);
    scatter_k<<<(E + 255) / 256, 256, 0, stream>>>(edge_index, cur, snd_s, rcv_s, E);

    edge_geom_k<<<EGB, 256, 0, stream>>>(positions, snd_s, rcv_s, flux_w, ef, polpart, E, ng);

    for (int l = 0; l < 2; ++l) {
        edge_mlp_k<<<E / 64, 256, 0, stream>>>(
            ef, snd_s, rcv_s, radial_w1, radial_b1, w2bf, scal, agg0, l, E);
        node_update_k<<<N / 4, 256, 0, stream>>>(
            scal, agg0, spec, prod_w, readout_w, ro2_w1, ro2_b1, ro2_w2,
            charge_w, q, out_nodeE, (l == 0) ? nE0 : nE1,
            l, (l == 1) ? 1 : 0, N);
    }

    coulomb_k<<<G_ * 64, 256, 0, stream>>>(q, positions, acc + 60, ng);
    graph_final_k<<<G_, 256, 0, stream>>>(spec, atomic_energies, formal_charges,
                                          positions, q, nE0, nE1, polpart,
                                          acc + 60, out, ng, N);
}

// Round 8
// 311.647 us; speedup vs baseline: 1.0761x; 1.0221x over previous
//
#include <hip/hip_runtime.h>
#include <math.h>

#define NEL 10
#define FD 64
#define NBES 8
#define GG 20
#define HML 16
#define EGB 512   // edge_geom blocks (pol partials sized to this)

typedef __attribute__((ext_vector_type(8))) short short8;
typedef __attribute__((ext_vector_type(4))) float f32x4;

__device__ __forceinline__ float wred(float v) {
    #pragma unroll
    for (int off = 32; off > 0; off >>= 1) v += __shfl_down(v, off, 64);
    return v;
}

__device__ __forceinline__ float silu(float h) {
    return h / (1.f + __expf(-h));
}

__device__ __forceinline__ unsigned short f2bf(float x) {
    unsigned int b = __float_as_uint(x);
    unsigned int r = (b + 0x7FFFu + ((b >> 16) & 1u)) >> 16;
    return (unsigned short)r;
}

// Fused: species via ballot (wave == node), scal init, E0/charge, edge histogram, agg0 zero.
__global__ __launch_bounds__(256) void setup_k(
    const float* __restrict__ attrs, const float* __restrict__ ae,
    const float* __restrict__ fc, const float* __restrict__ embed_w,
    const int* __restrict__ eidx, int* __restrict__ spec,
    float* __restrict__ q, float* __restrict__ out_nodeE,
    float* __restrict__ scal, float* __restrict__ agg0,
    int* __restrict__ cnt, int N_, int E_)
{
    int idx = blockIdx.x * 256 + threadIdx.x;   // grid = N*64 threads; wave = one node
    int lane = threadIdx.x & 63;
    int n = idx >> 6;
    bool pred = (lane < NEL) && (attrs[(size_t)n * NEL + lane] > 0.5f);
    unsigned long long m = __ballot(pred);
    int sp = (int)__builtin_ctzll(m);
    scal[idx] = embed_w[sp * FD + lane];
    agg0[idx] = 0.f;
    if (lane == 0) { spec[n] = sp; q[n] = fc[sp]; out_nodeE[n] = ae[sp]; }
    if (idx < E_) atomicAdd(&cnt[eidx[E_ + idx]], 1);
}

// Shuffle-based single-block scan + W1/W2 -> bf16 fragment-order conversion.
__global__ __launch_bounds__(1024) void scan_k(
    const int* __restrict__ cnt, int* __restrict__ cur,
    const float* __restrict__ w1, const float* __restrict__ w2,
    unsigned short* __restrict__ w1bf, unsigned short* __restrict__ w2bf, int N_)
{
    int t = threadIdx.x;
    // W2[l][k][f] -> w2bf[l][f*64+k]
    #pragma unroll
    for (int ii = 0; ii < 8; ++ii) {
        int idx = ii * 1024 + t;            // = l*4096 + f*64 + k
        int l = idx >> 12, rem = idx & 4095;
        int f = rem >> 6, k = rem & 63;
        w2bf[idx] = f2bf(w2[l * 4096 + k * 64 + f]);
    }
    // W1[l][j][m] -> w1bf[l*512 + m*8 + j]  (A-frag rows = k-output m, cols = input j)
    {
        int l = t >> 9, rem = t & 511;
        int m = rem >> 3, j = rem & 7;
        w1bf[t] = f2bf(w1[l * 512 + j * 64 + m]);
    }
    __shared__ int wtot[16];
    int lane = t & 63, wid = t >> 6;
    int base = t * 20;
    int c[20]; int s = 0;
    #pragma unroll
    for (int i = 0; i < 20; ++i) { int idx = base + i; c[i] = (idx < N_) ? cnt[idx] : 0; s += c[i]; }
    int v = s;
    #pragma unroll
    for (int off = 1; off < 64; off <<= 1) {
        int u = __shfl_up(v, off, 64);
        if (lane >= off) v += u;
    }
    if (lane == 63) wtot[wid] = v;
    __syncthreads();
    if (wid == 0 && lane < 16) {
        int wv = wtot[lane];
        #pragma unroll
        for (int off = 1; off < 16; off <<= 1) {
            int u = __shfl_up(wv, off, 64);
            if (lane >= off) wv += u;
        }
        wtot[lane] = wv;   // inclusive wave totals
    }
    __syncthreads();
    int ex = (wid > 0 ? wtot[wid - 1] : 0) + (v - s);
    #pragma unroll
    for (int i = 0; i < 20; ++i) {
        int idx = base + i;
        if (idx < N_) { cur[idx] = ex; ex += c[i]; }
    }
}

__global__ __launch_bounds__(256) void scatter_k(
    const int* __restrict__ eidx, int* __restrict__ cur,
    int* __restrict__ snd_s, int* __restrict__ rcv_s, int E_)
{
    int e = blockIdx.x * 256 + threadIdx.x;
    if (e < E_) {
        int r = eidx[E_ + e];
        int p = atomicAdd(&cur[r], 1);
        snd_s[p] = eidx[e];
        rcv_s[p] = r;
    }
}

// Edge geometry over SORTED edges: bessel basis -> bf16 (coalesced 16B stores), flux, pol partials.
__global__ __launch_bounds__(256) void edge_geom_k(
    const float* __restrict__ pos, const int* __restrict__ snd_s,
    const int* __restrict__ rcv_s, const float* __restrict__ flux_w,
    unsigned short* __restrict__ ef_bf, float* __restrict__ polpart, int E_, int ng)
{
    __shared__ float lpol[GG][3];
    int tid = threadIdx.x;
    if (tid < GG) { lpol[tid][0] = 0.f; lpol[tid][1] = 0.f; lpol[tid][2] = 0.f; }
    __syncthreads();
    float fw[NBES];
    #pragma unroll
    for (int i = 0; i < NBES; ++i) fw[i] = flux_w[i] + flux_w[NBES + i];
    const float PI = 3.14159265358979323846f;
    for (int p = blockIdx.x * 256 + tid; p < E_; p += EGB * 256) {
        int s = snd_s[p], r = rcv_s[p];
        float dx = pos[(size_t)r*3+0] - pos[(size_t)s*3+0];
        float dy = pos[(size_t)r*3+1] - pos[(size_t)s*3+1];
        float dz = pos[(size_t)r*3+2] - pos[(size_t)s*3+2];
        float len = sqrtf(dx*dx + dy*dy + dz*dz + 1e-12f);
        float x = len * 0.2f;
        float u = 0.f;
        if (x < 1.f) {
            float x2 = x * x;
            float x5 = x2 * x2 * x;
            u = 1.f - 21.f * x5 + 35.f * x5 * x - 15.f * x5 * x2;
        }
        float pref = 0.6324555320336759f / len * u;   // sqrt(2/5)/r * u
        float theta = PI * x;
        float s1, c1;
        __sincosf(theta, &s1, &c1);
        float c2 = 2.f * c1;
        float sp_ = 0.f, sn = s1;
        float flux = 0.f;
        unsigned int pk[4];
        #pragma unroll
        for (int i = 0; i < 4; ++i) {
            float r0 = pref * sn;
            float n1 = c2 * sn - sp_; sp_ = sn; sn = n1;
            float r1 = pref * sn;
            n1 = c2 * sn - sp_; sp_ = sn; sn = n1;
            flux += r0 * fw[2*i] + r1 * fw[2*i+1];
            pk[i] = (unsigned int)f2bf(r0) | ((unsigned int)f2bf(r1) << 16);
        }
        *(uint4*)&ef_bf[(size_t)p * NBES] = make_uint4(pk[0], pk[1], pk[2], pk[3]);
        int g = r / ng;
        atomicAdd(&lpol[g][0], flux * dx);
        atomicAdd(&lpol[g][1], flux * dy);
        atomicAdd(&lpol[g][2], flux * dz);
    }
    __syncthreads();
    if (tid < GG * 3) polpart[blockIdx.x * (GG * 3) + tid] = lpol[tid / 3][tid % 3];
}

// Radial MLP + message + segmented scatter. Wave-independent 16-edge tiles, zero barriers.
// Phase 1 is ALSO MFMA: h^T = W1^T_tiles @ ef^T (K zero-padded to 32, bias in k=8 slot).
// DS ops per wave: 4 write_b64 + 2 read_b128 (h transpose) + 16 w + 16 r (ctile) = ~38.
__global__ __launch_bounds__(256) void edge_mlp_k(
    const unsigned short* __restrict__ ef_bf, const int* __restrict__ snd_s,
    const int* __restrict__ rcv_s,
    const unsigned short* __restrict__ w1bf, const float* __restrict__ b1,
    const unsigned short* __restrict__ w2bf, const float* __restrict__ scal,
    float* __restrict__ agg0, int layer, int E_)
{
    __shared__ __align__(16) unsigned short hsh[4][16 * 72];  // 9216 B
    __shared__ __align__(16) float ctile[4][16 * 68];         // 17408 B (stride 68: 2-way free)

    int t = threadIdx.x, w = t >> 6, lane = t & 63;
    int mrow = lane & 15, quad = lane >> 4;
    int ebase = (blockIdx.x * 4 + w) * 16;

    // edge indices in registers (readlane broadcast later)
    int sv = snd_s[ebase + mrow];
    int rv = rcv_s[ebase + mrow];

    const short8 z8 = {0,0,0,0,0,0,0,0};
    // B-operand of phase-1: ef rows (quad0), bias-one slot (quad1 j=0)
    short8 b_ef = z8;
    if (quad == 0) b_ef = *(const short8*)&ef_bf[(size_t)(ebase + mrow) * NBES];
    else if (quad == 1) b_ef[0] = (short)0x3F80;     // bf16(1.0)
    // A-operand of phase-1: W1^T tiles (quad0), b1 (quad1 j=0)
    short8 a1[4];
    #pragma unroll
    for (int nt = 0; nt < 4; ++nt) {
        a1[nt] = z8;
        if (quad == 0) a1[nt] = *(const short8*)&w1bf[layer * 512 + (nt * 16 + mrow) * 8];
        else if (quad == 1) a1[nt][0] = (short)f2bf(b1[layer * FD + nt * 16 + mrow]);
    }
    // W2 B-fragments
    const unsigned short* wb = w2bf + layer * 4096;
    short8 bf0[4], bf1[4];
    #pragma unroll
    for (int nt = 0; nt < 4; ++nt) {
        bf0[nt] = *(const short8*)&wb[(nt * 16 + mrow) * 64 + quad * 8];
        bf1[nt] = *(const short8*)&wb[(nt * 16 + mrow) * 64 + 32 + quad * 8];
    }

    // phase 1: h^T[k][edge] via 4 MFMAs; lane -> (k = nt*16+quad*4+reg, edge = mrow)
    f32x4 zf = {0.f, 0.f, 0.f, 0.f};
    #pragma unroll
    for (int nt = 0; nt < 4; ++nt) {
        f32x4 c1 = __builtin_amdgcn_mfma_f32_16x16x32_bf16(a1[nt], b_ef, zf, 0, 0, 0);
        unsigned int p01 = (unsigned int)f2bf(silu(c1[0])) | ((unsigned int)f2bf(silu(c1[1])) << 16);
        unsigned int p23 = (unsigned int)f2bf(silu(c1[2])) | ((unsigned int)f2bf(silu(c1[3])) << 16);
        *(uint2*)&hsh[w][mrow * 72 + nt * 16 + quad * 4] = make_uint2(p01, p23);
    }

    // phase 2: A-frags from hsh (wave-local, in-order DS -> no barrier), 8 MFMAs
    short8 a0 = *(const short8*)&hsh[w][mrow * 72 + quad * 8];
    short8 a1b = *(const short8*)&hsh[w][mrow * 72 + 32 + quad * 8];
    f32x4 c[4];
    #pragma unroll
    for (int nt = 0; nt < 4; ++nt) {
        f32x4 cc = __builtin_amdgcn_mfma_f32_16x16x32_bf16(a0, bf0[nt], zf, 0, 0, 0);
        cc = __builtin_amdgcn_mfma_f32_16x16x32_bf16(a1b, bf1[nt], cc, 0, 0, 0);
        c[nt] = cc;
    }
    // transpose C: row = edge = quad*4+reg, col = f = nt*16+mrow
    #pragma unroll
    for (int nt = 0; nt < 4; ++nt)
        #pragma unroll
        for (int reg = 0; reg < 4; ++reg)
            ctile[w][(quad * 4 + reg) * 68 + nt * 16 + mrow] = c[nt][reg];

    // epilogue: segmented reduce over the wave's 16 sorted positions (f = lane)
    int curR = __builtin_amdgcn_readlane(rv, 0);
    float run = 0.f;
    #pragma unroll
    for (int pp = 0; pp < 16; ++pp) {
        int s = __builtin_amdgcn_readlane(sv, pp);
        int r = __builtin_amdgcn_readlane(rv, pp);
        float v = ctile[w][pp * 68 + lane] * scal[(size_t)s * FD + lane];
        if (r != curR) {
            atomicAdd(&agg0[(size_t)curR * FD + lane], run);
            run = v; curR = r;
        } else {
            run += v;
        }
    }
    atomicAdd(&agg0[(size_t)curR * FD + lane], run);
}

// Node update: scalars' = agg/16 + (agg/16)^2 + scal*prod_w[spec]; per-node energies to scratch.
__global__ __launch_bounds__(256) void node_update_k(
    float* __restrict__ scal, float* __restrict__ agg0,
    const int* __restrict__ spec, const float* __restrict__ prod_w,
    const float* __restrict__ readout_w, const float* __restrict__ ro2_w1,
    const float* __restrict__ ro2_b1, const float* __restrict__ ro2_w2,
    const float* __restrict__ charge_w, float* __restrict__ q,
    float* __restrict__ out_nodeE, float* __restrict__ nEl,
    int layer, int last, int N_)
{
    __shared__ float vsh[4][FD];
    int wid = threadIdx.x >> 6, lane = threadIdx.x & 63;
    int n = blockIdx.x * 4 + wid;
    int sp = spec[n];
    size_t idx = (size_t)n * FD + lane;
    float a = agg0[idx] * 0.0625f;
    agg0[idx] = 0.f;                       // pre-zero for next layer
    float v = a + a * a + scal[idx] * prod_w[(layer * NEL + sp) * FD + lane];
    scal[idx] = v;

    float ne;
    if (!last) {
        ne = wred(v * readout_w[layer * FD + lane]);
    } else {
        vsh[wid][lane] = v;
        __syncthreads();
        float h = 0.f;
        if (lane < HML) {
            h = ro2_b1[lane];
            for (int ff = 0; ff < FD; ++ff) h += vsh[wid][ff] * ro2_w1[ff * HML + lane];
            h = silu(h) * ro2_w2[lane];
        }
        ne = wred(h);
    }
    float qs = wred(v * charge_w[layer * FD + lane]);
    if (lane == 0) {
        nEl[n] = ne;
        out_nodeE[n] += ne;
        q[n] += qs;
    }
}

// Direct screened Coulomb: block = (graph, 64-wide i-chunk, 250-wide j-slice). 1280 blocks.
__global__ __launch_bounds__(256) void coulomb_k(
    const float* __restrict__ q, const float* __restrict__ pos,
    float* __restrict__ eel, int ng)
{
    __shared__ float qs[250], jx[250], jy[250], jz[250];
    __shared__ float wsum[4];
    int bid = blockIdx.x;
    int g = bid >> 6, rem = bid & 63;
    int ic = rem >> 2, jc = rem & 3;
    int tid = threadIdx.x, lane = tid & 63, w = tid >> 6;
    const float* qg = q + (size_t)g * ng;
    const float* pg = pos + (size_t)g * ng * 3;
    int jbase = jc * 250;
    if (tid < 250) {
        int j = jbase + tid;
        qs[tid] = qg[j];
        jx[tid] = pg[(size_t)j*3+0]; jy[tid] = pg[(size_t)j*3+1]; jz[tid] = pg[(size_t)j*3+2];
    }
    __syncthreads();
    int i = ic * 64 + lane;
    float acc = 0.f;
    if (i < ng) {
        float qi = qg[i];
        float xi = pg[(size_t)i*3+0], yi = pg[(size_t)i*3+1], zi = pg[(size_t)i*3+2];
        for (int jj = w; jj < 250; jj += 4) {     // jj wave-uniform -> LDS broadcast
            int j = jbase + jj;
            float dx = xi - jx[jj], dy = yi - jy[jj], dz = zi - jz[jj];
            float d2 = dx*dx + dy*dy + dz*dz + 1e-12f;
            float rinv = __frsqrt_rn(d2);
            float r = d2 * rinv;
            float x = 0.5f * r;
            float tt = __frcp_rn(1.f + 0.3275911f * x);
            float poly = ((((1.061405429f*tt - 1.453152027f)*tt + 1.421413741f)*tt
                           - 0.284496736f)*tt + 0.254829592f)*tt;
            float erfv = 1.f - poly * __expf(-x * x);
            float kern = (j == i) ? 0.f : erfv * rinv;
            acc += qi * qs[jj] * kern;
        }
    }
    acc = wred(acc);
    if (lane == 0) wsum[w] = acc;
    __syncthreads();
    if (tid == 0) atomicAdd(&eel[g], 0.5f * (wsum[0] + wsum[1] + wsum[2] + wsum[3]));
}

// Per-graph reductions + final output assembly (runs after coulomb).
__global__ __launch_bounds__(256) void graph_final_k(
    const int* __restrict__ spec, const float* __restrict__ ae,
    const float* __restrict__ fc, const float* __restrict__ pos,
    const float* __restrict__ q, const float* __restrict__ nE0,
    const float* __restrict__ nE1, const float* __restrict__ polpart,
    const float* __restrict__ eel, float* __restrict__ out,
    int ng, int N_)
{
    __shared__ float red[4][8];
    __shared__ float res[7];
    int g = blockIdx.x;
    int tid = threadIdx.x, wid = tid >> 6, lane = tid & 63;
    float se0 = 0.f, s0 = 0.f, s1 = 0.f, sq = 0.f, p0 = 0.f, p1 = 0.f, p2 = 0.f;
    for (int n = g * ng + tid; n < (g + 1) * ng; n += 256) {
        int sp = spec[n];
        float fq = fc[sp];
        se0 += ae[sp];
        s0 += nE0[n];
        s1 += nE1[n];
        sq += q[n];
        p0 += fq * pos[(size_t)n*3+0];
        p1 += fq * pos[(size_t)n*3+1];
        p2 += fq * pos[(size_t)n*3+2];
    }
    // fold edge-flux pol partials in parallel
    for (int b = tid; b < EGB; b += 256) {
        p0 += polpart[b * (GG * 3) + g * 3 + 0];
        p1 += polpart[b * (GG * 3) + g * 3 + 1];
        p2 += polpart[b * (GG * 3) + g * 3 + 2];
    }
    float vals[7] = {se0, s0, s1, sq, p0, p1, p2};
    #pragma unroll
    for (int k = 0; k < 7; ++k) {
        float r = wred(vals[k]);
        if (lane == 0) red[wid][k] = r;
    }
    __syncthreads();
    if (tid < 7) res[tid] = red[0][tid] + red[1][tid] + red[2][tid] + red[3][tid];
    __syncthreads();
    if (tid == 0) {
        int G_ = GG;
        float a0 = res[0], a1 = res[1], a2 = res[2];
        out[g] = a0 + a1 + a2 + eel[g];             // total_energy
        float* contrib = out + G_ + N_;             // contributions [G,3]
        contrib[g*3+0] = a0; contrib[g*3+1] = a1; contrib[g*3+2] = a2;
        float* pol = contrib + G_ * 3;              // pol [G,3]
        pol[g*3+0] = res[4]; pol[g*3+1] = res[5]; pol[g*3+2] = res[6];
        float* qt = pol + G_ * 3;                   // total_charge [G]
        qt[g] = res[3];
    }
}

extern "C" void kernel_launch(void* const* d_in, const int* in_sizes, int n_in,
                              void* d_out, int out_size, void* d_ws, size_t ws_size,
                              hipStream_t stream)
{
    const float* node_attrs      = (const float*)d_in[0];
    const float* positions       = (const float*)d_in[1];
    const int*   edge_index      = (const int*)d_in[2];
    const float* atomic_energies = (const float*)d_in[5];
    const float* embed_w         = (const float*)d_in[6];
    const float* radial_w1       = (const float*)d_in[7];
    const float* radial_b1       = (const float*)d_in[8];
    const float* radial_w2       = (const float*)d_in[9];
    const float* prod_w          = (const float*)d_in[10];
    const float* readout_w       = (const float*)d_in[11];
    const float* ro2_w1          = (const float*)d_in[12];
    const float* ro2_b1          = (const float*)d_in[13];
    const float* ro2_w2          = (const float*)d_in[14];
    const float* charge_w        = (const float*)d_in[15];
    const float* flux_w          = (const float*)d_in[16];
    const float* formal_charges  = (const float*)d_in[17];

    int N = in_sizes[0] / NEL;     // 20000
    int E = in_sizes[2] / 2;       // 320000
    const int G_ = GG;             // 20
    int ng = N / G_;               // 1000

    float* ws      = (float*)d_ws;
    float* scal    = ws;                               // [N,64]
    float* agg0    = scal + (size_t)N * FD;            // [N,64]
    unsigned short* ef_bf = (unsigned short*)(agg0 + (size_t)N * FD); // [E,8] bf16 sorted
    float* q       = (float*)(ef_bf + (size_t)E * NBES);             // [N]
    int*   spec    = (int*)(q + N);                    // [N]
    float* nE0     = (float*)(spec + N);               // [N]
    float* nE1     = nE0 + N;                          // [N]
    float* polpart = nE1 + N;                          // [EGB*60]
    int*   cnt     = (int*)(polpart + EGB * (GG * 3)); // [N]
    float* acc     = (float*)(cnt + N);                // [160] (contiguous w/ cnt for 1 memset)
    int*   cur     = (int*)(acc + 160);                // [N]
    int*   snd_s   = cur + N;                          // [E]
    int*   rcv_s   = snd_s + E;                        // [E]
    unsigned short* w2bf = (unsigned short*)(rcv_s + E); // [2*4096] bf16
    unsigned short* w1bf = w2bf + 8192;                  // [2*512] bf16

    float* out = (float*)d_out;
    float* out_nodeE = out + G_;

    hipMemsetAsync(cnt, 0, (size_t)N * sizeof(int) + 160 * sizeof(float), stream);

    setup_k<<<(N * FD) / 256, 256, 0, stream>>>(
        node_attrs, atomic_energies, formal_charges, embed_w, edge_index,
        spec, q, out_nodeE, scal, agg0, cnt, N, E);
    scan_k<<<1, 1024, 0, stream>>>(cnt, cur, radial_w1, radial_w2, w1bf, w2bf, N);
    scatter_k<<<(E + 255) / 256, 256, 0, stream>>>(edge_index, cur, snd_s, rcv_s, E);

    edge_geom_k<<<EGB, 256, 0, stream>>>(positions, snd_s, rcv_s, flux_w, ef_bf, polpart, E, ng);

    for (int l = 0; l < 2; ++l) {
        edge_mlp_k<<<E / 64, 256, 0, stream>>>(
            ef_bf, snd_s, rcv_s, w1bf, radial_b1, w2bf, scal, agg0, l, E);
        node_update_k<<<N / 4, 256, 0, stream>>>(
            scal, agg0, spec, prod_w, readout_w, ro2_w1, ro2_b1, ro2_w2,
            charge_w, q, out_nodeE, (l == 0) ? nE0 : nE1,
            l, (l == 1) ? 1 : 0, N);
    }

    coulomb_k<<<G_ * 64, 256, 0, stream>>>(q, positions, acc + 60, ng);
    graph_final_k<<<G_, 256, 0, stream>>>(spec, atomic_energies, formal_charges,
                                          positions, q, nE0, nE1, polpart,
                                          acc + 60, out, ng, N);
}